// Round 11
// baseline (296.128 us; speedup 1.0000x reference)
//
#include <hip/hip_runtime.h>
#include <hip/hip_bf16.h>
#include <stdint.h>

// Problem constants (hard-coded): B=4, S=2048, D=1024, H=16, HD=64
#define B_   4
#define S_   2048
#define D_   1024
#define H_   16
#define HD_  64
#define BH_  (B_*H_)      // 64
#define MROWS (B_*S_)     // 8192

typedef short  short8  __attribute__((ext_vector_type(8)));
typedef float  floatx4 __attribute__((ext_vector_type(4)));

__device__ __forceinline__ ushort f2bf(float f) {
    union { float f; uint32_t u; } v; v.f = f;
    uint32_t u = v.u;
    return (ushort)((u + 0x7FFFu + ((u >> 16) & 1u)) >> 16);   // RNE
}
__device__ __forceinline__ float u2f(uint32_t u) {
    union { uint32_t u; float f; } v; v.u = u; return v.f;
}
__device__ __forceinline__ uint32_t f2u(float f) {
    union { float f; uint32_t u; } v; v.f = f; return v.u;
}

// async global->LDS, 16 B per lane. LDS dest MUST be wave-uniform base +
// lane*16 (m104/m108) — any swizzling must happen on the GLOBAL address.
__device__ __forceinline__ void gl_lds16(const ushort* g, ushort* l) {
    __builtin_amdgcn_global_load_lds(
        (const __attribute__((address_space(1))) unsigned int*)g,
        (__attribute__((address_space(3))) unsigned int*)l,
        16, 0, 0);
}

// ---------------------------------------------------------------- fused prep
// blocks [0,3072): Wqkv^T->bf16 ; [3072,4096): Wout^T->bf16 ; [4096,12288): x->bf16
__global__ __launch_bounds__(256)
void k_prep(const float* __restrict__ x, const float* __restrict__ Wqkv,
            const float* __restrict__ Wout,
            ushort* __restrict__ Xbf, ushort* __restrict__ WqkvT, ushort* __restrict__ WoutT) {
    __shared__ float tile[32][33];
    int blk = blockIdx.x;
    int tid = threadIdx.x;
    if (blk >= 4096) {
        int i = (blk - 4096) * 1024 + tid * 4;
        float4 f = *(const float4*)(x + i);
        ushort4 o; o.x = f2bf(f.x); o.y = f2bf(f.y); o.z = f2bf(f.z); o.w = f2bf(f.w);
        *(ushort4*)(Xbf + i) = o;
        return;
    }
    const float* in; ushort* out; int R, C, bx, by;
    if (blk < 3072) { in = Wqkv; out = WqkvT; R = D_; C = 3 * D_; bx = (blk % 96) * 32; by = (blk / 96) * 32; }
    else            { int b2 = blk - 3072; in = Wout; out = WoutT; R = D_; C = D_; bx = (b2 % 32) * 32; by = (b2 / 32) * 32; }
    int tx = tid & 31, ty = tid >> 5;
    #pragma unroll
    for (int j = 0; j < 32; j += 8)
        tile[ty + j][tx] = in[(size_t)(by + ty + j) * C + bx + tx];
    __syncthreads();
    #pragma unroll
    for (int j = 0; j < 32; j += 8)
        out[(size_t)(bx + ty + j) * R + by + tx] = f2bf(tile[tx][ty + j]);
}

// ---------------------------------------------------------------- GEMM (r7 structure + pointer-increment staging)
// Post-mortem r8/r10: both 256^2 ports failed (r8: 1 blk/CU coarse; r10:
// drain-to-0 per tile == m218 V1 == no pipeline). Reverted to the proven
// r7 128x128 / 4 blocks/CU structure. New in r11: staging via 8 precomputed
// per-thread chunk pointers incremented by BK per tile (k_attn's trick) —
// deletes the per-tile 64-bit address rederivation from the staging window.
// EPI=0 epilogue: LDS bounce + fused RoPE (q/k) + direct V^T store.
#define BM 128
#define BN 128
#define BK 64

template<int EPI>
__global__ __launch_bounds__(256)
void k_gemm(const ushort* __restrict__ A, const ushort* __restrict__ Bt,
            float* __restrict__ outF,
            ushort* __restrict__ q_out, ushort* __restrict__ k_out, ushort* __restrict__ vT_out,
            int M, int N, int K,
            const float* __restrict__ cosT, const float* __restrict__ sinT) {
    __shared__ __align__(16) ushort smem[128 * 132];   // 33 KB: K-loop uses first 32KB as As|Bs
    ushort* As = smem;
    ushort* Bs = smem + BM * 64;
    int tid  = threadIdx.x;
    int lane = tid & 63;
    int wave = tid >> 6;
    int quad = lane >> 4;
    int l16  = lane & 15;
    int bm = blockIdx.y * BM;
    int bn = blockIdx.x * BN;
    int wm = (wave >> 1) * 64;
    int wn = (wave & 1) * 64;

    floatx4 acc[4][4] = {};

    // per-thread staging pointers: 4 A-chunks + 4 B-chunks, advance BK/tile
    const ushort* ap[4];
    const ushort* bp[4];
    #pragma unroll
    for (int i = 0; i < 4; i++) {
        int c   = i * 256 + tid;
        int row = c >> 3;
        int gc  = (c & 7) ^ (row & 7);    // permuted global chunk
        ap[i] = &A [(size_t)(bm + row) * K + gc * 8];
        bp[i] = &Bt[(size_t)(bn + row) * K + gc * 8];
    }

    for (int k0 = 0; k0 < K; k0 += BK) {
        __syncthreads();
        #pragma unroll
        for (int i = 0; i < 4; i++) {
            int c = i * 256 + tid;
            gl_lds16(ap[i], &As[c * 8]);
            gl_lds16(bp[i], &Bs[c * 8]);
            ap[i] += BK; bp[i] += BK;
        }
        __syncthreads();
        #pragma unroll
        for (int kk = 0; kk < 2; kk++) {
            short8 af[4], bf[4];
            #pragma unroll
            for (int mt = 0; mt < 4; mt++)
                af[mt] = *(const short8*)&As[(wm + mt * 16 + l16) * 64 +
                                             (((kk * 4 + quad) ^ (l16 & 7)) << 3)];
            #pragma unroll
            for (int nt = 0; nt < 4; nt++)
                bf[nt] = *(const short8*)&Bs[(wn + nt * 16 + l16) * 64 +
                                             (((kk * 4 + quad) ^ (l16 & 7)) << 3)];
            #pragma unroll
            for (int mt = 0; mt < 4; mt++)
                #pragma unroll
                for (int nt = 0; nt < 4; nt++)
                    acc[mt][nt] = __builtin_amdgcn_mfma_f32_16x16x32_bf16(af[mt], bf[nt], acc[mt][nt], 0, 0, 0);
        }
    }

    if (EPI == 1) {
        #pragma unroll
        for (int mt = 0; mt < 4; mt++)
            #pragma unroll
            for (int nt = 0; nt < 4; nt++)
                #pragma unroll
                for (int r = 0; r < 4; r++) {
                    int row = bm + wm + mt * 16 + quad * 4 + r;
                    int col = bn + wn + nt * 16 + l16;
                    outF[(size_t)row * N + col] = acc[mt][nt][r];
                }
        return;
    }

    // ---- EPI==0: LDS bounce, then fused RoPE (q/k) or direct V^T store
    __syncthreads();                     // K-loop reads of As/Bs done
    #pragma unroll
    for (int mt = 0; mt < 4; mt++)
        #pragma unroll
        for (int nt = 0; nt < 4; nt++)
            #pragma unroll
            for (int r = 0; r < 4; r++) {
                int srow = wm + mt * 16 + quad * 4 + r;
                int scol = wn + nt * 16 + l16;
                smem[srow * 132 + scol] = f2bf(acc[mt][nt][r]);
            }
    __syncthreads();

    int which  = bn >> 10;               // block-uniform: 0=q 1=k 2=v
    int hbase2 = (bn & 1023) >> 6;       // head at col 0 of tile
    int bIdx   = bm >> 11, sloc0 = bm & 2047;

    if (which == 2) {
        // V: column gather -> VbT[bh][hd][sloc0 .. sloc0+127]
        int c  = tid >> 1;               // tile column 0..127
        int hf = tid & 1;                // row half
        int h  = hbase2 + (c >> 6);
        int hd = c & 63;
        size_t obase = ((size_t)((bIdx * H_ + h) * HD_ + hd)) * S_ + sloc0 + hf * 64;
        #pragma unroll
        for (int j8 = 0; j8 < 8; j8++) {
            ushort t8v[8];
            #pragma unroll
            for (int j = 0; j < 8; j++)
                t8v[j] = smem[(hf * 64 + j8 * 8 + j) * 132 + c];
            *(uint4*)&vT_out[obase + j8 * 8] = *(uint4*)t8v;
        }
        return;
    }

    ushort* dst = (which == 0) ? q_out : k_out;
    #pragma unroll
    for (int i = 0; i < 8; i++) {
        int g    = i * 256 + tid;
        int srow = g >> 4;               // 0..127
        int cc   = (g & 15) * 8;         // 0..120
        int sloc = sloc0 + srow;
        int h    = hbase2 + (cc >> 6);
        int hd0  = cc & 63;
        size_t didx = ((size_t)((bIdx * H_ + h) * S_ + sloc)) * HD_ + hd0;

        int  i0 = cc & 31;
        bool up = (cc & 32) != 0;
        int  cb = cc & ~63;
        const ushort* in = &smem[srow * 132 + cb + 2 * i0];
        uint2 wA = *(const uint2*)&in[0];
        uint2 wB = *(const uint2*)&in[4];
        uint2 wC = *(const uint2*)&in[8];
        uint2 wD = *(const uint2*)&in[12];
        uint32_t w[8] = { wA.x, wA.y, wB.x, wB.y, wC.x, wC.y, wD.x, wD.y };
        float cs[8], sn[8];
        *(float4*)&cs[0] = *(const float4*)&cosT[sloc * 32 + i0];
        *(float4*)&cs[4] = *(const float4*)&cosT[sloc * 32 + i0 + 4];
        *(float4*)&sn[0] = *(const float4*)&sinT[sloc * 32 + i0];
        *(float4*)&sn[4] = *(const float4*)&sinT[sloc * 32 + i0 + 4];
        ushort o[8];
        #pragma unroll
        for (int e = 0; e < 8; e++) {
            float x1 = u2f(w[e] << 16);
            float x2 = u2f(w[e] & 0xFFFF0000u);
            float ov = up ? (x1 * sn[e] + x2 * cs[e]) : (x1 * cs[e] - x2 * sn[e]);
            if (which == 0) ov *= 0.1803368801f;   // (1/8)*log2(e)
            o[e] = f2bf(ov);
        }
        *(uint4*)&dst[didx] = *(uint4*)o;
    }
}

// ---------------------------------------------------------------- flash attention v13 (unchanged)
__global__ __launch_bounds__(256, 4)
void k_attn(const ushort* __restrict__ Q, const ushort* __restrict__ K,
            const ushort* __restrict__ VT, ushort* __restrict__ O) {
    __shared__ __align__(16) ushort Ks[64 * 64];       // [key][hd]  swizzled
    __shared__ __align__(16) ushort Vt[64 * 64];       // [hd][key]  swizzled
    __shared__ __align__(16) ushort Pst[4][32 * 64];   // per-wave [qrow][key] swizzled

    int tid  = threadIdx.x;
    int lane = tid & 63;
    int wave = tid >> 6;
    int quad = lane >> 4;
    int l16  = lane & 15;

    int bh   = blockIdx.x & 63;
    int p    = blockIdx.x >> 6;          // pair index 0..15
    int sA   = p;                        // light strip (64 rows)
    int sB   = 31 - p;                   // heavy strip (64 rows)
    size_t hbase = (size_t)bh * S_ * HD_;
    size_t vbase = (size_t)bh * HD_ * S_;

    int mrow[2] = { sA * 64 + wave * 16, sB * 64 + wave * 16 };

    short8 qf[2][2];
    #pragma unroll
    for (int m = 0; m < 2; m++)
        #pragma unroll
        for (int h = 0; h < 2; h++)
            qf[m][h] = *(const short8*)&Q[hbase + (size_t)(mrow[m] + l16) * HD_ + quad * 8 + h * 32];

    short8 ones;
    #pragma unroll
    for (int e = 0; e < 8; e++) ones[e] = (short)0x3F80;   // bf16 1.0

    floatx4 acc[2][4] = {};
    floatx4 accl[2] = {};
    const floatx4 z4 = {0.f, 0.f, 0.f, 0.f};

    // staging pointers (advance by constant per tile)
    int c0r = tid >> 3;                     // chunk row for i=0 (0..31)
    int c1r = (256 + tid) >> 3;             // chunk row for i=1 (32..63)
    const ushort* kp0 = &K[hbase + (size_t)c0r * HD_ + (((tid & 7) ^ (c0r & 7)) << 3)];
    const ushort* kp1 = &K[hbase + (size_t)c1r * HD_ + (((tid & 7) ^ (c1r & 7)) << 3)];
    const ushort* vp0 = &VT[vbase + (size_t)c0r * S_ + (((tid & 7) ^ (c0r & 7)) << 3)];
    const ushort* vp1 = &VT[vbase + (size_t)c1r * S_ + (((tid & 7) ^ (c1r & 7)) << 3)];

    int nk = sB + 1;

    // prologue: tile 0 -> regs; pointers advance to tile 1
    uint4 rk0 = *(const uint4*)kp0;
    uint4 rk1 = *(const uint4*)kp1;
    uint4 rv0 = *(const uint4*)vp0;
    uint4 rv1 = *(const uint4*)vp1;
    kp0 += 64 * HD_; kp1 += 64 * HD_; vp0 += 64; vp1 += 64;

    for (int kb = 0; kb < nk; kb++) {
        int k0 = kb * 64;
        __syncthreads();                 // everyone done computing tile kb-1
        // write staged regs (tile kb) into LDS
        *(uint4*)&Ks[tid * 8]         = rk0;
        *(uint4*)&Ks[(256 + tid) * 8] = rk1;
        *(uint4*)&Vt[tid * 8]         = rv0;
        *(uint4*)&Vt[(256 + tid) * 8] = rv1;
        if (kb + 1 < nk) {               // issue tile kb+1 loads; they land
            rk0 = *(const uint4*)kp0;    // during this tile's compute
            rk1 = *(const uint4*)kp1;
            rv0 = *(const uint4*)vp0;
            rv1 = *(const uint4*)vp1;
            kp0 += 64 * HD_; kp1 += 64 * HD_; vp0 += 64; vp1 += 64;
        }
        __syncthreads();                 // tile kb visible in LDS

        bool act0 = (k0 <= mrow[0] + 15);    // m=1 always active inside loop

        // ---- QK kt-outer: kf loaded once, shared across m; exp2+pack fused
        #pragma unroll
        for (int kt = 0; kt < 4; kt++) {
            short8 kf0 = *(const short8*)&Ks[(kt * 16 + l16) * 64 + ((quad ^ (l16 & 7)) << 3)];
            short8 kf1 = *(const short8*)&Ks[(kt * 16 + l16) * 64 + (((4 + quad) ^ (l16 & 7)) << 3)];

            __builtin_amdgcn_s_setprio(1);
            floatx4 s1 = __builtin_amdgcn_mfma_f32_16x16x32_bf16(kf0, qf[1][0], z4, 0, 0, 0);
            s1         = __builtin_amdgcn_mfma_f32_16x16x32_bf16(kf1, qf[1][1], s1, 0, 0, 0);
            floatx4 s0 = z4;
            if (act0) {
                s0 = __builtin_amdgcn_mfma_f32_16x16x32_bf16(kf0, qf[0][0], z4, 0, 0, 0);
                s0 = __builtin_amdgcn_mfma_f32_16x16x32_bf16(kf1, qf[0][1], s0, 0, 0, 0);
            }
            __builtin_amdgcn_s_setprio(0);

            int pc = (kt * 4 + quad) ^ (l16 & 14);
            #pragma unroll
            for (int m = 0; m < 2; m++) {
                if (m == 0 && !act0) continue;
                floatx4 sm = (m == 0) ? s0 : s1;
                bool needMask = (k0 + 63 > mrow[m]);
                int qr = mrow[m] + l16;
                float pp[4];
                #pragma unroll
                for (int r = 0; r < 4; r++) {
                    float v = __builtin_amdgcn_exp2f(sm[r]);
                    if (needMask) {
                        int kc = k0 + kt * 16 + quad * 4 + r;
                        if (kc > qr) v = 0.0f;
                    }
                    pp[r] = v;
                }
                uint2 pk;
                asm("v_cvt_pk_bf16_f32 %0, %1, %2" : "=v"(pk.x) : "v"(pp[0]), "v"(pp[1]));
                asm("v_cvt_pk_bf16_f32 %0, %1, %2" : "=v"(pk.y) : "v"(pp[2]), "v"(pp[3]));
                *(uint2*)&Pst[wave][(m * 16 + l16) * 64 + pc * 4] = pk;
            }
        }

        // ---- PV (+ MFMA-pipe row sums), vb shared across m
        bool act[2] = { act0, true };
        #pragma unroll
        for (int k2 = 0; k2 < 2; k2++) {
            short8 vb[4];
            #pragma unroll
            for (int nt = 0; nt < 4; nt++)
                vb[nt] = *(const short8*)&Vt[(nt * 16 + l16) * 64 +
                                             (((k2 * 4 + quad) ^ (l16 & 7)) << 3)];
            int pe = (k2 * 8 + quad * 2) ^ (l16 & 14);
            __builtin_amdgcn_s_setprio(1);
            #pragma unroll
            for (int m = 0; m < 2; m++) {
                if (!act[m]) continue;
                short8 pa = *(const short8*)&Pst[wave][(m * 16 + l16) * 64 + pe * 4];
                #pragma unroll
                for (int nt = 0; nt < 4; nt++)
                    acc[m][nt] = __builtin_amdgcn_mfma_f32_16x16x32_bf16(pa, vb[nt], acc[m][nt], 0, 0, 0);
                accl[m] = __builtin_amdgcn_mfma_f32_16x16x32_bf16(pa, ones, accl[m], 0, 0, 0);
            }
            __builtin_amdgcn_s_setprio(0);
        }
    }

    int b = bh >> 4, h = bh & 15;
    #pragma unroll
    for (int m = 0; m < 2; m++)
        #pragma unroll
        for (int r = 0; r < 4; r++) {
            float inv = __builtin_amdgcn_rcpf(accl[m][r]);
            int qr = mrow[m] + quad * 4 + r;
            #pragma unroll
            for (int nt = 0; nt < 4; nt++)
                O[((size_t)(b * S_ + qr)) * D_ + h * HD_ + nt * 16 + l16] = f2bf(acc[m][nt][r] * inv);
        }
}

// ---------------------------------------------------------------- launch
extern "C" void kernel_launch(void* const* d_in, const int* in_sizes, int n_in,
                              void* d_out, int out_size, void* d_ws, size_t ws_size,
                              hipStream_t stream) {
    const float* x    = (const float*)d_in[0];
    const float* cosT = (const float*)d_in[1];
    const float* sinT = (const float*)d_in[2];
    // d_in[3] = mask : causal, computed analytically — never read
    const float* Wqkv = (const float*)d_in[4];
    const float* Wout = (const float*)d_in[5];
    float* out = (float*)d_out;

    ushort* ws = (ushort*)d_ws;
    ushort* Xbf    = ws;                           // 8192*1024 (dead after GEMM0)
    ushort* WqkvT  = Xbf    + (size_t)MROWS * D_;  // 3072*1024
    ushort* WoutT  = WqkvT  + (size_t)3 * D_ * D_; // 1024*1024
    ushort* Qb     = WoutT  + (size_t)D_ * D_;     // 64*2048*64
    ushort* Kb     = Qb     + (size_t)BH_ * S_ * HD_;
    ushort* VbT    = Kb     + (size_t)BH_ * S_ * HD_;   // V stored transposed directly
    ushort* AO     = Xbf;                          // alias: Xbf dead after GEMM0

    k_prep<<<12288, 256, 0, stream>>>(x, Wqkv, Wout, Xbf, WqkvT, WoutT);
    k_gemm<0><<<dim3(3 * D_ / BN, MROWS / BM), 256, 0, stream>>>(Xbf, WqkvT, nullptr, Qb, Kb, VbT,
                                                                 MROWS, 3 * D_, D_, cosT, sinT);
    k_attn<<<1024, 256, 0, stream>>>(Qb, Kb, VbT, AO);
    k_gemm<1><<<dim3(D_ / BN, MROWS / BM), 256, 0, stream>>>(AO, WoutT, out, nullptr, nullptr, nullptr,
                                                             MROWS, D_, D_, nullptr, nullptr);
}

// Round 12
// 285.752 us; speedup vs baseline: 1.0363x; 1.0363x over previous
//
#include <hip/hip_runtime.h>
#include <hip/hip_bf16.h>
#include <stdint.h>

// Problem constants (hard-coded): B=4, S=2048, D=1024, H=16, HD=64
#define B_   4
#define S_   2048
#define D_   1024
#define H_   16
#define HD_  64
#define BH_  (B_*H_)      // 64
#define MROWS (B_*S_)     // 8192

typedef short  short8  __attribute__((ext_vector_type(8)));
typedef float  floatx4 __attribute__((ext_vector_type(4)));

__device__ __forceinline__ ushort f2bf(float f) {
    union { float f; uint32_t u; } v; v.f = f;
    uint32_t u = v.u;
    return (ushort)((u + 0x7FFFu + ((u >> 16) & 1u)) >> 16);   // RNE
}
__device__ __forceinline__ float u2f(uint32_t u) {
    union { uint32_t u; float f; } v; v.u = u; return v.f;
}
__device__ __forceinline__ uint32_t f2u(float f) {
    union { float f; uint32_t u; } v; v.f = f; return v.u;
}

// async global->LDS, 16 B per lane. LDS dest MUST be wave-uniform base +
// lane*16 (m104/m108) — any swizzling must happen on the GLOBAL address.
__device__ __forceinline__ void gl_lds16(const ushort* g, ushort* l) {
    __builtin_amdgcn_global_load_lds(
        (const __attribute__((address_space(1))) unsigned int*)g,
        (__attribute__((address_space(3))) unsigned int*)l,
        16, 0, 0);
}

// ---------------------------------------------------------------- fused prep
// blocks [0,3072): Wqkv^T->bf16 ; [3072,4096): Wout^T->bf16 ; [4096,12288): x->bf16
__global__ __launch_bounds__(256)
void k_prep(const float* __restrict__ x, const float* __restrict__ Wqkv,
            const float* __restrict__ Wout,
            ushort* __restrict__ Xbf, ushort* __restrict__ WqkvT, ushort* __restrict__ WoutT) {
    __shared__ float tile[32][33];
    int blk = blockIdx.x;
    int tid = threadIdx.x;
    if (blk >= 4096) {
        int i = (blk - 4096) * 1024 + tid * 4;
        float4 f = *(const float4*)(x + i);
        ushort4 o; o.x = f2bf(f.x); o.y = f2bf(f.y); o.z = f2bf(f.z); o.w = f2bf(f.w);
        *(ushort4*)(Xbf + i) = o;
        return;
    }
    const float* in; ushort* out; int R, C, bx, by;
    if (blk < 3072) { in = Wqkv; out = WqkvT; R = D_; C = 3 * D_; bx = (blk % 96) * 32; by = (blk / 96) * 32; }
    else            { int b2 = blk - 3072; in = Wout; out = WoutT; R = D_; C = D_; bx = (b2 % 32) * 32; by = (b2 / 32) * 32; }
    int tx = tid & 31, ty = tid >> 5;
    #pragma unroll
    for (int j = 0; j < 32; j += 8)
        tile[ty + j][tx] = in[(size_t)(by + ty + j) * C + bx + tx];
    __syncthreads();
    #pragma unroll
    for (int j = 0; j < 32; j += 8)
        out[(size_t)(bx + ty + j) * R + by + tx] = f2bf(tile[tx][ty + j]);
}

// ---------------------------------------------------------------- GEMM (r7 exact — best verified: gemm0 70.7us)
// Post-mortem r11: persistent per-thread staging pointers regressed (-8%):
// the k0-indexed form lets the compiler keep bases in SGPRs (saddr+voffset);
// VGPR pointer pairs add v_add chains in the staging window. Reverted.
// EPI=0 epilogue: LDS bounce + fused RoPE (q/k) + direct V^T store.
#define BM 128
#define BN 128
#define BK 64

template<int EPI>
__global__ __launch_bounds__(256)
void k_gemm(const ushort* __restrict__ A, const ushort* __restrict__ Bt,
            float* __restrict__ outF,
            ushort* __restrict__ q_out, ushort* __restrict__ k_out, ushort* __restrict__ vT_out,
            int M, int N, int K,
            const float* __restrict__ cosT, const float* __restrict__ sinT) {
    __shared__ __align__(16) ushort smem[128 * 132];   // 33 KB: K-loop uses first 32KB as As|Bs
    ushort* As = smem;
    ushort* Bs = smem + BM * 64;
    int tid  = threadIdx.x;
    int lane = tid & 63;
    int wave = tid >> 6;
    int quad = lane >> 4;
    int l16  = lane & 15;
    int bm = blockIdx.y * BM;
    int bn = blockIdx.x * BN;
    int wm = (wave >> 1) * 64;
    int wn = (wave & 1) * 64;

    floatx4 acc[4][4] = {};

    for (int k0 = 0; k0 < K; k0 += BK) {
        __syncthreads();
        #pragma unroll
        for (int i = 0; i < 4; i++) {
            int c   = i * 256 + tid;
            int row = c >> 3;
            int gc  = (c & 7) ^ (row & 7);    // permuted global chunk
            gl_lds16(&A[(size_t)(bm + row) * K + k0 + gc * 8],  &As[c * 8]);
            gl_lds16(&Bt[(size_t)(bn + row) * K + k0 + gc * 8], &Bs[c * 8]);
        }
        __syncthreads();
        #pragma unroll
        for (int kk = 0; kk < 2; kk++) {
            short8 af[4], bf[4];
            #pragma unroll
            for (int mt = 0; mt < 4; mt++)
                af[mt] = *(const short8*)&As[(wm + mt * 16 + l16) * 64 +
                                             (((kk * 4 + quad) ^ (l16 & 7)) << 3)];
            #pragma unroll
            for (int nt = 0; nt < 4; nt++)
                bf[nt] = *(const short8*)&Bs[(wn + nt * 16 + l16) * 64 +
                                             (((kk * 4 + quad) ^ (l16 & 7)) << 3)];
            #pragma unroll
            for (int mt = 0; mt < 4; mt++)
                #pragma unroll
                for (int nt = 0; nt < 4; nt++)
                    acc[mt][nt] = __builtin_amdgcn_mfma_f32_16x16x32_bf16(af[mt], bf[nt], acc[mt][nt], 0, 0, 0);
        }
    }

    if (EPI == 1) {
        #pragma unroll
        for (int mt = 0; mt < 4; mt++)
            #pragma unroll
            for (int nt = 0; nt < 4; nt++)
                #pragma unroll
                for (int r = 0; r < 4; r++) {
                    int row = bm + wm + mt * 16 + quad * 4 + r;
                    int col = bn + wn + nt * 16 + l16;
                    outF[(size_t)row * N + col] = acc[mt][nt][r];
                }
        return;
    }

    // ---- EPI==0: LDS bounce, then fused RoPE (q/k) or direct V^T store
    __syncthreads();                     // K-loop reads of As/Bs done
    #pragma unroll
    for (int mt = 0; mt < 4; mt++)
        #pragma unroll
        for (int nt = 0; nt < 4; nt++)
            #pragma unroll
            for (int r = 0; r < 4; r++) {
                int srow = wm + mt * 16 + quad * 4 + r;
                int scol = wn + nt * 16 + l16;
                smem[srow * 132 + scol] = f2bf(acc[mt][nt][r]);
            }
    __syncthreads();

    int which  = bn >> 10;               // block-uniform: 0=q 1=k 2=v
    int hbase2 = (bn & 1023) >> 6;       // head at col 0 of tile
    int bIdx   = bm >> 11, sloc0 = bm & 2047;

    if (which == 2) {
        // V: column gather -> VbT[bh][hd][sloc0 .. sloc0+127]
        int c  = tid >> 1;               // tile column 0..127
        int hf = tid & 1;                // row half
        int h  = hbase2 + (c >> 6);
        int hd = c & 63;
        size_t obase = ((size_t)((bIdx * H_ + h) * HD_ + hd)) * S_ + sloc0 + hf * 64;
        #pragma unroll
        for (int j8 = 0; j8 < 8; j8++) {
            ushort t8v[8];
            #pragma unroll
            for (int j = 0; j < 8; j++)
                t8v[j] = smem[(hf * 64 + j8 * 8 + j) * 132 + c];
            *(uint4*)&vT_out[obase + j8 * 8] = *(uint4*)t8v;
        }
        return;
    }

    ushort* dst = (which == 0) ? q_out : k_out;
    #pragma unroll
    for (int i = 0; i < 8; i++) {
        int g    = i * 256 + tid;
        int srow = g >> 4;               // 0..127
        int cc   = (g & 15) * 8;         // 0..120
        int sloc = sloc0 + srow;
        int h    = hbase2 + (cc >> 6);
        int hd0  = cc & 63;
        size_t didx = ((size_t)((bIdx * H_ + h) * S_ + sloc)) * HD_ + hd0;

        int  i0 = cc & 31;
        bool up = (cc & 32) != 0;
        int  cb = cc & ~63;
        const ushort* in = &smem[srow * 132 + cb + 2 * i0];
        uint2 wA = *(const uint2*)&in[0];
        uint2 wB = *(const uint2*)&in[4];
        uint2 wC = *(const uint2*)&in[8];
        uint2 wD = *(const uint2*)&in[12];
        uint32_t w[8] = { wA.x, wA.y, wB.x, wB.y, wC.x, wC.y, wD.x, wD.y };
        float cs[8], sn[8];
        *(float4*)&cs[0] = *(const float4*)&cosT[sloc * 32 + i0];
        *(float4*)&cs[4] = *(const float4*)&cosT[sloc * 32 + i0 + 4];
        *(float4*)&sn[0] = *(const float4*)&sinT[sloc * 32 + i0];
        *(float4*)&sn[4] = *(const float4*)&sinT[sloc * 32 + i0 + 4];
        ushort o[8];
        #pragma unroll
        for (int e = 0; e < 8; e++) {
            float x1 = u2f(w[e] << 16);
            float x2 = u2f(w[e] & 0xFFFF0000u);
            float ov = up ? (x1 * sn[e] + x2 * cs[e]) : (x1 * cs[e] - x2 * sn[e]);
            if (which == 0) ov *= 0.1803368801f;   // (1/8)*log2(e)
            o[e] = f2bf(ov);
        }
        *(uint4*)&dst[didx] = *(uint4*)o;
    }
}

// ---------------------------------------------------------------- flash attention v13 (unchanged)
__global__ __launch_bounds__(256, 4)
void k_attn(const ushort* __restrict__ Q, const ushort* __restrict__ K,
            const ushort* __restrict__ VT, ushort* __restrict__ O) {
    __shared__ __align__(16) ushort Ks[64 * 64];       // [key][hd]  swizzled
    __shared__ __align__(16) ushort Vt[64 * 64];       // [hd][key]  swizzled
    __shared__ __align__(16) ushort Pst[4][32 * 64];   // per-wave [qrow][key] swizzled

    int tid  = threadIdx.x;
    int lane = tid & 63;
    int wave = tid >> 6;
    int quad = lane >> 4;
    int l16  = lane & 15;

    int bh   = blockIdx.x & 63;
    int p    = blockIdx.x >> 6;          // pair index 0..15
    int sA   = p;                        // light strip (64 rows)
    int sB   = 31 - p;                   // heavy strip (64 rows)
    size_t hbase = (size_t)bh * S_ * HD_;
    size_t vbase = (size_t)bh * HD_ * S_;

    int mrow[2] = { sA * 64 + wave * 16, sB * 64 + wave * 16 };

    short8 qf[2][2];
    #pragma unroll
    for (int m = 0; m < 2; m++)
        #pragma unroll
        for (int h = 0; h < 2; h++)
            qf[m][h] = *(const short8*)&Q[hbase + (size_t)(mrow[m] + l16) * HD_ + quad * 8 + h * 32];

    short8 ones;
    #pragma unroll
    for (int e = 0; e < 8; e++) ones[e] = (short)0x3F80;   // bf16 1.0

    floatx4 acc[2][4] = {};
    floatx4 accl[2] = {};
    const floatx4 z4 = {0.f, 0.f, 0.f, 0.f};

    // staging pointers (advance by constant per tile)
    int c0r = tid >> 3;                     // chunk row for i=0 (0..31)
    int c1r = (256 + tid) >> 3;             // chunk row for i=1 (32..63)
    const ushort* kp0 = &K[hbase + (size_t)c0r * HD_ + (((tid & 7) ^ (c0r & 7)) << 3)];
    const ushort* kp1 = &K[hbase + (size_t)c1r * HD_ + (((tid & 7) ^ (c1r & 7)) << 3)];
    const ushort* vp0 = &VT[vbase + (size_t)c0r * S_ + (((tid & 7) ^ (c0r & 7)) << 3)];
    const ushort* vp1 = &VT[vbase + (size_t)c1r * S_ + (((tid & 7) ^ (c1r & 7)) << 3)];

    int nk = sB + 1;

    // prologue: tile 0 -> regs; pointers advance to tile 1
    uint4 rk0 = *(const uint4*)kp0;
    uint4 rk1 = *(const uint4*)kp1;
    uint4 rv0 = *(const uint4*)vp0;
    uint4 rv1 = *(const uint4*)vp1;
    kp0 += 64 * HD_; kp1 += 64 * HD_; vp0 += 64; vp1 += 64;

    for (int kb = 0; kb < nk; kb++) {
        int k0 = kb * 64;
        __syncthreads();                 // everyone done computing tile kb-1
        // write staged regs (tile kb) into LDS
        *(uint4*)&Ks[tid * 8]         = rk0;
        *(uint4*)&Ks[(256 + tid) * 8] = rk1;
        *(uint4*)&Vt[tid * 8]         = rv0;
        *(uint4*)&Vt[(256 + tid) * 8] = rv1;
        if (kb + 1 < nk) {               // issue tile kb+1 loads; they land
            rk0 = *(const uint4*)kp0;    // during this tile's compute
            rk1 = *(const uint4*)kp1;
            rv0 = *(const uint4*)vp0;
            rv1 = *(const uint4*)vp1;
            kp0 += 64 * HD_; kp1 += 64 * HD_; vp0 += 64; vp1 += 64;
        }
        __syncthreads();                 // tile kb visible in LDS

        bool act0 = (k0 <= mrow[0] + 15);    // m=1 always active inside loop

        // ---- QK kt-outer: kf loaded once, shared across m; exp2+pack fused
        #pragma unroll
        for (int kt = 0; kt < 4; kt++) {
            short8 kf0 = *(const short8*)&Ks[(kt * 16 + l16) * 64 + ((quad ^ (l16 & 7)) << 3)];
            short8 kf1 = *(const short8*)&Ks[(kt * 16 + l16) * 64 + (((4 + quad) ^ (l16 & 7)) << 3)];

            __builtin_amdgcn_s_setprio(1);
            floatx4 s1 = __builtin_amdgcn_mfma_f32_16x16x32_bf16(kf0, qf[1][0], z4, 0, 0, 0);
            s1         = __builtin_amdgcn_mfma_f32_16x16x32_bf16(kf1, qf[1][1], s1, 0, 0, 0);
            floatx4 s0 = z4;
            if (act0) {
                s0 = __builtin_amdgcn_mfma_f32_16x16x32_bf16(kf0, qf[0][0], z4, 0, 0, 0);
                s0 = __builtin_amdgcn_mfma_f32_16x16x32_bf16(kf1, qf[0][1], s0, 0, 0, 0);
            }
            __builtin_amdgcn_s_setprio(0);

            int pc = (kt * 4 + quad) ^ (l16 & 14);
            #pragma unroll
            for (int m = 0; m < 2; m++) {
                if (m == 0 && !act0) continue;
                floatx4 sm = (m == 0) ? s0 : s1;
                bool needMask = (k0 + 63 > mrow[m]);
                int qr = mrow[m] + l16;
                float pp[4];
                #pragma unroll
                for (int r = 0; r < 4; r++) {
                    float v = __builtin_amdgcn_exp2f(sm[r]);
                    if (needMask) {
                        int kc = k0 + kt * 16 + quad * 4 + r;
                        if (kc > qr) v = 0.0f;
                    }
                    pp[r] = v;
                }
                uint2 pk;
                asm("v_cvt_pk_bf16_f32 %0, %1, %2" : "=v"(pk.x) : "v"(pp[0]), "v"(pp[1]));
                asm("v_cvt_pk_bf16_f32 %0, %1, %2" : "=v"(pk.y) : "v"(pp[2]), "v"(pp[3]));
                *(uint2*)&Pst[wave][(m * 16 + l16) * 64 + pc * 4] = pk;
            }
        }

        // ---- PV (+ MFMA-pipe row sums), vb shared across m
        bool act[2] = { act0, true };
        #pragma unroll
        for (int k2 = 0; k2 < 2; k2++) {
            short8 vb[4];
            #pragma unroll
            for (int nt = 0; nt < 4; nt++)
                vb[nt] = *(const short8*)&Vt[(nt * 16 + l16) * 64 +
                                             (((k2 * 4 + quad) ^ (l16 & 7)) << 3)];
            int pe = (k2 * 8 + quad * 2) ^ (l16 & 14);
            __builtin_amdgcn_s_setprio(1);
            #pragma unroll
            for (int m = 0; m < 2; m++) {
                if (!act[m]) continue;
                short8 pa = *(const short8*)&Pst[wave][(m * 16 + l16) * 64 + pe * 4];
                #pragma unroll
                for (int nt = 0; nt < 4; nt++)
                    acc[m][nt] = __builtin_amdgcn_mfma_f32_16x16x32_bf16(pa, vb[nt], acc[m][nt], 0, 0, 0);
                accl[m] = __builtin_amdgcn_mfma_f32_16x16x32_bf16(pa, ones, accl[m], 0, 0, 0);
            }
            __builtin_amdgcn_s_setprio(0);
        }
    }

    int b = bh >> 4, h = bh & 15;
    #pragma unroll
    for (int m = 0; m < 2; m++)
        #pragma unroll
        for (int r = 0; r < 4; r++) {
            float inv = __builtin_amdgcn_rcpf(accl[m][r]);
            int qr = mrow[m] + quad * 4 + r;
            #pragma unroll
            for (int nt = 0; nt < 4; nt++)
                O[((size_t)(b * S_ + qr)) * D_ + h * HD_ + nt * 16 + l16] = f2bf(acc[m][nt][r] * inv);
        }
}

// ---------------------------------------------------------------- launch
extern "C" void kernel_launch(void* const* d_in, const int* in_sizes, int n_in,
                              void* d_out, int out_size, void* d_ws, size_t ws_size,
                              hipStream_t stream) {
    const float* x    = (const float*)d_in[0];
    const float* cosT = (const float*)d_in[1];
    const float* sinT = (const float*)d_in[2];
    // d_in[3] = mask : causal, computed analytically — never read
    const float* Wqkv = (const float*)d_in[4];
    const float* Wout = (const float*)d_in[5];
    float* out = (float*)d_out;

    ushort* ws = (ushort*)d_ws;
    ushort* Xbf    = ws;                           // 8192*1024 (dead after GEMM0)
    ushort* WqkvT  = Xbf    + (size_t)MROWS * D_;  // 3072*1024
    ushort* WoutT  = WqkvT  + (size_t)3 * D_ * D_; // 1024*1024
    ushort* Qb     = WoutT  + (size_t)D_ * D_;     // 64*2048*64
    ushort* Kb     = Qb     + (size_t)BH_ * S_ * HD_;
    ushort* VbT    = Kb     + (size_t)BH_ * S_ * HD_;   // V stored transposed directly
    ushort* AO     = Xbf;                          // alias: Xbf dead after GEMM0

    k_prep<<<12288, 256, 0, stream>>>(x, Wqkv, Wout, Xbf, WqkvT, WoutT);
    k_gemm<0><<<dim3(3 * D_ / BN, MROWS / BM), 256, 0, stream>>>(Xbf, WqkvT, nullptr, Qb, Kb, VbT,
                                                                 MROWS, 3 * D_, D_, cosT, sinT);
    k_attn<<<1024, 256, 0, stream>>>(Qb, Kb, VbT, AO);
    k_gemm<1><<<dim3(D_ / BN, MROWS / BM), 256, 0, stream>>>(AO, WoutT, out, nullptr, nullptr, nullptr,
                                                             MROWS, D_, D_, nullptr, nullptr);
}